// Round 1
// baseline (1836.160 us; speedup 1.0000x reference)
//
#include <hip/hip_runtime.h>
#include <cstdint>
#include <cstddef>

using short8  = __attribute__((ext_vector_type(8))) short;
using floatx4 = __attribute__((ext_vector_type(4))) float;
typedef unsigned short u16;

constexpr int NN = 30000;   // nodes
constexpr int NE = 60000;   // edges / messages
constexpr int BATCH = 256;
constexpr int HH = 256;
constexpr int LL = 32;
constexpr int VV = 40;
constexpr int NBOND = 4;
constexpr int TT = 6;
constexpr int PT = 1536, PA = 1280, PB = 2560;

__device__ __forceinline__ float b2f(u16 h) {
  union { unsigned u; float f; } v; v.u = ((unsigned)h) << 16; return v.f;
}
__device__ __forceinline__ u16 f2b(float f) {
  union { float f; unsigned u; } v; v.f = f;
  unsigned r = v.u + 0x7FFFu + ((v.u >> 16) & 1u);
  return (u16)(r >> 16);
}

// ---------------------------------------------------------------------------
// Generic bf16 MFMA GEMM:  C[M,256] = epilogue(A[M,K] @ B[K,256])
// A row-major bf16 (lda = K, multiple of 8), Bt = B^T row-major bf16 [256,K].
// 128x128 tile per block, 4 waves in 2x2, 16x16x32 MFMA, BK=32.
// ---------------------------------------------------------------------------
template<int RELU_BIAS>
__global__ __launch_bounds__(256) void gemm_bt_kernel(
    const u16* __restrict__ A, int lda, int M,
    const u16* __restrict__ Bt, int K,
    u16* __restrict__ C, int ldc, const float* __restrict__ bias)
{
  // pitch 56 (=32+24) keeps 16B row alignment and 2-way-max bank aliasing
  __shared__ __align__(16) u16 As[128][56];
  __shared__ __align__(16) u16 Bs[128][56];
  const int tid  = threadIdx.x;
  const int wave = tid >> 6, lane = tid & 63;
  const int wm = wave >> 1, wn = wave & 1;
  const int lr = lane & 15, lk = (lane >> 4) * 8;
  const long rowbase = (long)blockIdx.x * 128;
  const int  colbase = blockIdx.y * 128;

  floatx4 acc[4][4];
#pragma unroll
  for (int i = 0; i < 4; i++)
#pragma unroll
    for (int j = 0; j < 4; j++) acc[i][j] = {0.f, 0.f, 0.f, 0.f};

  for (int k0 = 0; k0 < K; k0 += 32) {
#pragma unroll
    for (int r = 0; r < 2; r++) {
      int c = tid + 256 * r;
      int row = c >> 2, cc = (c & 3) * 8;
      long grow = rowbase + row;
      uint4 av = {0u, 0u, 0u, 0u};
      if (grow < M) av = *(const uint4*)(A + grow * (long)lda + k0 + cc);
      *(uint4*)(&As[row][cc]) = av;
      uint4 bv = *(const uint4*)(Bt + (long)(colbase + row) * K + k0 + cc);
      *(uint4*)(&Bs[row][cc]) = bv;
    }
    __syncthreads();
    short8 af[4], bf[4];
#pragma unroll
    for (int mt = 0; mt < 4; mt++) af[mt] = *(const short8*)(&As[wm * 64 + mt * 16 + lr][lk]);
#pragma unroll
    for (int nt = 0; nt < 4; nt++) bf[nt] = *(const short8*)(&Bs[wn * 64 + nt * 16 + lr][lk]);
#pragma unroll
    for (int mt = 0; mt < 4; mt++)
#pragma unroll
      for (int nt = 0; nt < 4; nt++)
        acc[mt][nt] = __builtin_amdgcn_mfma_f32_16x16x32_bf16(af[mt], bf[nt], acc[mt][nt], 0, 0, 0);
    __syncthreads();
  }

  const int rq = (lane >> 4) * 4;
#pragma unroll
  for (int mt = 0; mt < 4; mt++) {
#pragma unroll
    for (int nt = 0; nt < 4; nt++) {
      int gcol = colbase + wn * 64 + nt * 16 + lr;
#pragma unroll
      for (int r2 = 0; r2 < 4; r2++) {
        long grow = rowbase + wm * 64 + mt * 16 + rq + r2;
        if (grow < M) {
          float v = acc[mt][nt][r2];
          if (RELU_BIAS) { v += bias[gcol]; v = v > 0.f ? v : 0.f; }
          C[grow * (long)ldc + gcol] = f2b(v);
        }
      }
    }
  }
}

// ---------------------------------------------------------------------------
// small utility kernels
// ---------------------------------------------------------------------------
__global__ __launch_bounds__(256) void cvt_f2b4_kernel(const float* __restrict__ in,
                                                       u16* __restrict__ out, long n4)
{
  long i = (long)blockIdx.x * 256 + threadIdx.x;
  if (i >= n4) return;
  float4 v = ((const float4*)in)[i];
  ushort4 o; o.x = f2b(v.x); o.y = f2b(v.y); o.z = f2b(v.z); o.w = f2b(v.w);
  ((ushort4*)out)[i] = o;
}

// Bt[n][k] = bf16(W[k][n]), zero-padded k in [K, Kpad). W is [K,256] f32.
__global__ __launch_bounds__(256) void transpose_w_kernel(const float* __restrict__ W,
                                                          int K, int Kpad, u16* __restrict__ Bt)
{
  int idx = blockIdx.x * 256 + threadIdx.x;
  int total = 256 * Kpad;
  if (idx >= total) return;
  int n = idx / Kpad, k = idx - n * Kpad;
  Bt[idx] = (k < K) ? f2b(W[(long)k * 256 + n]) : (u16)0;
}

// masked neighbor lists: out[t][i] = graph[i] * em[t][graph[i]]
__global__ __launch_bounds__(256) void mask_kernel(const int* __restrict__ graph,
                                                   const int* __restrict__ em,
                                                   int* __restrict__ outm, int count, int estride)
{
  int t = blockIdx.y;
  int i = blockIdx.x * 256 + threadIdx.x;
  if (i >= count) return;
  int v = graph[i];
  outm[(long)t * count + i] = v * em[(long)t * estride + v];
}

// h1 = relu(pre + b_h) * pad
__global__ __launch_bounds__(256) void h1_kernel(const u16* __restrict__ pre,
                                                 const float* __restrict__ bh,
                                                 u16* __restrict__ out)
{
  long i = (long)blockIdx.x * 256 + threadIdx.x;
  if (i >= (long)NE * 64) return;
  int row = (int)(i >> 6);
  int c = ((int)i & 63) * 4;
  ushort4 p = *(const ushort4*)(pre + (long)row * 256 + c);
  float4 b = *(const float4*)(bh + c);
  float x0 = b2f(p.x) + b.x, x1 = b2f(p.y) + b.y, x2 = b2f(p.z) + b.z, x3 = b2f(p.w) + b.w;
  if (row == 0) { x0 = x1 = x2 = x3 = 0.f; }
  else { x0 = fmaxf(x0, 0.f); x1 = fmaxf(x1, 0.f); x2 = fmaxf(x2, 0.f); x3 = fmaxf(x3, 0.f); }
  ushort4 o; o.x = f2b(x0); o.y = f2b(x1); o.z = f2b(x2); o.w = f2b(x3);
  *(ushort4*)(out + (long)row * 256 + c) = o;
}

#define ACC4(ii) { ushort4 g_ = *(const ushort4*)(tab + (long)(ii) * 256 + c); \
  a0 += b2f(g_.x); a1 += b2f(g_.y); a2 += b2f(g_.z); a3 += b2f(g_.w); }

// out[e] = relu(pre[e] + sum_j tab[idx6[e][j]] + bias) * pad(e)
__global__ __launch_bounds__(256) void gather_e_kernel(
    const u16* __restrict__ tab, const u16* __restrict__ pre,
    const float* __restrict__ bias, const int* __restrict__ idx6,
    u16* __restrict__ out)
{
  int wave = threadIdx.x >> 6, lane = threadIdx.x & 63;
  int row = blockIdx.x * 4 + wave;
  if (row >= NE) return;
  const int* ip = idx6 + (long)row * 6;
  int i0 = ip[0], i1 = ip[1], i2 = ip[2], i3 = ip[3], i4 = ip[4], i5 = ip[5];
  int c = lane * 4;
  ushort4 p = *(const ushort4*)(pre + (long)row * 256 + c);
  float a0 = b2f(p.x), a1 = b2f(p.y), a2 = b2f(p.z), a3 = b2f(p.w);
  ACC4(i0) ACC4(i1) ACC4(i2) ACC4(i3) ACC4(i4) ACC4(i5)
  float4 b = *(const float4*)(bias + c);
  a0 += b.x; a1 += b.y; a2 += b.z; a3 += b.w;
  if (row == 0) { a0 = a1 = a2 = a3 = 0.f; }
  else { a0 = fmaxf(a0, 0.f); a1 = fmaxf(a1, 0.f); a2 = fmaxf(a2, 0.f); a3 = fmaxf(a3, 0.f); }
  ushort4 o; o.x = f2b(a0); o.y = f2b(a1); o.z = f2b(a2); o.w = f2b(a3);
  *(ushort4*)(out + (long)row * 256 + c) = o;
}

// node[n] = relu(fo[n] + sum_j tab[idx6[n][j]] + b_o) * vm[n]
__global__ __launch_bounds__(256) void gather_n_kernel(
    const u16* __restrict__ tab, const u16* __restrict__ fo,
    const float* __restrict__ bias, const int* __restrict__ idx6,
    const int* __restrict__ vm, u16* __restrict__ out)
{
  int wave = threadIdx.x >> 6, lane = threadIdx.x & 63;
  int row = blockIdx.x * 4 + wave;
  if (row >= NN) return;
  const int* ip = idx6 + (long)row * 6;
  int i0 = ip[0], i1 = ip[1], i2 = ip[2], i3 = ip[3], i4 = ip[4], i5 = ip[5];
  int c = lane * 4;
  ushort4 p = *(const ushort4*)(fo + (long)row * 256 + c);
  float a0 = b2f(p.x), a1 = b2f(p.y), a2 = b2f(p.z), a3 = b2f(p.w);
  ACC4(i0) ACC4(i1) ACC4(i2) ACC4(i3) ACC4(i4) ACC4(i5)
  float4 b = *(const float4*)(bias + c);
  a0 += b.x; a1 += b.y; a2 += b.z; a3 += b.w;
  a0 = fmaxf(a0, 0.f); a1 = fmaxf(a1, 0.f); a2 = fmaxf(a2, 0.f); a3 = fmaxf(a3, 0.f);
  if (vm[row] == 0) { a0 = a1 = a2 = a3 = 0.f; }
  ushort4 o; o.x = f2b(a0); o.y = f2b(a1); o.z = f2b(a2); o.w = f2b(a3);
  *(ushort4*)(out + (long)row * 256 + c) = o;
}
#undef ACC4

__device__ __forceinline__ int lbound(const int* __restrict__ a, int n, int key) {
  int lo = 0, hi = n;
  while (lo < hi) { int mid = (lo + hi) >> 1; if (a[mid] < key) lo = mid + 1; else hi = mid; }
  return lo;
}

// gv[b][h] = sum over segment of node2graph==b (sorted)
__global__ __launch_bounds__(256) void gvec_kernel(const u16* __restrict__ node,
                                                   const int* __restrict__ n2g,
                                                   float* __restrict__ gv)
{
  int b = blockIdx.x, h = threadIdx.x;
  int lo = lbound(n2g, NN, b), hi = lbound(n2g, NN, b + 1);
  float s = 0.f;
  for (int n = lo; n < hi; n++) s += b2f(node[(long)n * 256 + h]);
  gv[b * 256 + h] = s;
}

// scatter node rows of this step into head-input matrices
__global__ __launch_bounds__(256) void head_gather_kernel(int t,
    const u16* __restrict__ node,
    const int* __restrict__ tstep, const int* __restrict__ txid,
    const int* __restrict__ astep, const int* __restrict__ axid,
    const int* __restrict__ bstep, const int* __restrict__ bzid,
    u16* __restrict__ tv, u16* __restrict__ av, u16* __restrict__ bv,
    u16* __restrict__ wbin)
{
  int wave = threadIdx.x >> 6, lane = threadIdx.x & 63;
  int r = blockIdx.x * 4 + wave;
  int c = lane * 4;
  if (r < PT) {
    if (tstep[r] != t) return;
    ushort4 v = *(const ushort4*)(node + (long)txid[r] * 256 + c);
    *(ushort4*)(tv + (long)r * 544 + 256 + c) = v;
  } else if (r < PT + PA) {
    int i = r - PT;
    if (astep[i] != t) return;
    ushort4 v = *(const ushort4*)(node + (long)axid[i] * 256 + c);
    *(ushort4*)(av + (long)i * 544 + 256 + c) = v;
  } else if (r < PT + PA + PB) {
    int i = r - PT - PA;
    if (bstep[i] != t) return;
    ushort4 v = *(const ushort4*)(node + (long)bzid[i] * 256 + c);
    *(ushort4*)(bv + (long)i * 800 + 512 + c) = v;
    *(ushort4*)(wbin + (long)i * 288 + c) = v;
  }
}

// fill gvec / src / one-hot segments of head inputs (after all steps)
__global__ __launch_bounds__(256) void build_static_kernel(
    const float* __restrict__ gvec, const float* __restrict__ src,
    const int* __restrict__ tstep, const int* __restrict__ tbid,
    const int* __restrict__ astep, const int* __restrict__ abid,
    const int* __restrict__ bstep, const int* __restrict__ bbid,
    const int* __restrict__ blabel, const int* __restrict__ batype,
    u16* __restrict__ tv, u16* __restrict__ av, u16* __restrict__ bv,
    u16* __restrict__ wbin, u16* __restrict__ rbin)
{
  int wave = threadIdx.x >> 6, lane = threadIdx.x & 63;
  int r = blockIdx.x * 4 + wave;
  int c = lane * 4;
  if (r < PT) {
    int st = tstep[r], bid = tbid[r];
    const float* g = gvec + ((long)st * BATCH + bid) * 256;
    u16* d = tv + (long)r * 544;
    float4 g4 = *(const float4*)(g + c);
    d[c] = f2b(g4.x); d[c + 1] = f2b(g4.y); d[c + 2] = f2b(g4.z); d[c + 3] = f2b(g4.w);
    if (lane < 8) {
      float4 s4 = *(const float4*)(src + bid * 32 + c);
      d[512 + c] = f2b(s4.x); d[512 + c + 1] = f2b(s4.y);
      d[512 + c + 2] = f2b(s4.z); d[512 + c + 3] = f2b(s4.w);
    }
  } else if (r < PT + PA) {
    int i = r - PT;
    int st = astep[i], bid = abid[i];
    const float* g = gvec + ((long)st * BATCH + bid) * 256;
    u16* d = av + (long)i * 544;
    float4 g4 = *(const float4*)(g + c);
    d[c] = f2b(g4.x); d[c + 1] = f2b(g4.y); d[c + 2] = f2b(g4.z); d[c + 3] = f2b(g4.w);
    if (lane < 8) {
      float4 s4 = *(const float4*)(src + bid * 32 + c);
      d[512 + c] = f2b(s4.x); d[512 + c + 1] = f2b(s4.y);
      d[512 + c + 2] = f2b(s4.z); d[512 + c + 3] = f2b(s4.w);
    }
  } else if (r < PT + PA + PB) {
    int i = r - PT - PA;
    int st = bstep[i], bid = bbid[i];
    const float* g = gvec + ((long)st * BATCH + bid) * 256;
    u16* d = bv + (long)i * 800;
    float4 g4 = *(const float4*)(g + c);
    d[c] = f2b(g4.x); d[c + 1] = f2b(g4.y); d[c + 2] = f2b(g4.z); d[c + 3] = f2b(g4.w);
    if (lane < 8) {
      float4 s4 = *(const float4*)(src + bid * 32 + c);
      d[768 + c] = f2b(s4.x); d[768 + c + 1] = f2b(s4.y);
      d[768 + c + 2] = f2b(s4.z); d[768 + c + 3] = f2b(s4.w);
      int bl = blabel[i];
      u16* wd = wbin + (long)i * 288 + 256;
      for (int q = 0; q < 4; q++) {
        int k = c + q;   // 0..31
        wd[k] = f2b((k < NBOND && bl == k) ? 1.f : 0.f);
      }
    }
    if (lane < 16) {
      int at = batype[i];
      u16* rd = rbin + (long)i * 320 + 256;
      for (int q = 0; q < 4; q++) {
        int k = c + q;   // 0..63
        rd[k] = f2b((k < VV && at == k) ? 1.f : 0.f);
      }
    }
  }
}

// rbin[r][0:256] = sum_{j in [gs[r], r)} wb[j] * (blabel[j] > 0)
__global__ __launch_bounds__(256) void hist_kernel(
    const u16* __restrict__ wb, const int* __restrict__ gs_arr,
    const int* __restrict__ blabel, u16* __restrict__ rbin)
{
  int wave = threadIdx.x >> 6, lane = threadIdx.x & 63;
  int r = blockIdx.x * 4 + wave;
  if (r >= PB) return;
  int c = lane * 4;
  float a0 = 0.f, a1 = 0.f, a2 = 0.f, a3 = 0.f;
  int gs = gs_arr[r];
  for (int j = gs; j < r; j++) {
    if (blabel[j] > 0) {
      ushort4 g = *(const ushort4*)(wb + (long)j * 256 + c);
      a0 += b2f(g.x); a1 += b2f(g.y); a2 += b2f(g.z); a3 += b2f(g.w);
    }
  }
  u16* rd = rbin + (long)r * 320;
  rd[c] = f2b(a0); rd[c + 1] = f2b(a1); rd[c + 2] = f2b(a2); rd[c + 3] = f2b(a3);
}

// topo: BCE-with-logits, one wave per row
__global__ __launch_bounds__(256) void topo_loss_kernel(
    const u16* __restrict__ hidden, const float* __restrict__ w2,
    const float* __restrict__ b2, const int* __restrict__ label,
    float* __restrict__ out)
{
  int wave = threadIdx.x >> 6, lane = threadIdx.x & 63;
  int r = blockIdx.x * 4 + wave;
  if (r >= PT) return;
  const u16* h = hidden + (long)r * 256;
  int c = lane * 4;
  ushort4 hv = *(const ushort4*)(h + c);
  float4 wv = *(const float4*)(w2 + c);
  float s = b2f(hv.x) * wv.x + b2f(hv.y) * wv.y + b2f(hv.z) * wv.z + b2f(hv.w) * wv.w;
#pragma unroll
  for (int off = 32; off > 0; off >>= 1) s += __shfl_xor(s, off);
  if (lane == 0) {
    float l = s + b2[0];
    float y = (float)label[r];
    float sp = fmaxf(l, 0.f) + log1pf(expf(-fabsf(l)));
    atomicAdd(out, (sp - l * y) * (1.0f / BATCH));
  }
}

// cross-entropy over NC classes (NC<=64), one wave per row
template<int NC>
__global__ __launch_bounds__(256) void ce_loss_kernel(
    const u16* __restrict__ hidden, const float* __restrict__ w2,
    const float* __restrict__ b2, const int* __restrict__ label,
    int rows, float* __restrict__ out)
{
  int wave = threadIdx.x >> 6, lane = threadIdx.x & 63;
  int r = blockIdx.x * 4 + wave;
  if (r >= rows) return;
  const u16* h = hidden + (long)r * 256;
  bool valid = lane < NC;
  float s = valid ? b2[lane] : 0.f;
  for (int c = 0; c < 256; c++) {
    float hv = b2f(h[c]);
    if (valid) s += hv * w2[c * NC + lane];
  }
  float logit = valid ? s : -1e30f;
  float m = logit;
#pragma unroll
  for (int off = 32; off > 0; off >>= 1) m = fmaxf(m, __shfl_xor(m, off));
  float e = valid ? expf(logit - m) : 0.f;
#pragma unroll
  for (int off = 32; off > 0; off >>= 1) e += __shfl_xor(e, off);
  float lse = m + logf(e);
  int lb = label[r];
  float ll = __shfl(logit, lb);
  if (lane == 0) atomicAdd(out, (lse - ll) * (1.0f / BATCH));
}

// ---------------------------------------------------------------------------
extern "C" void kernel_launch(void* const* d_in, const int* in_sizes, int n_in,
                              void* d_out, int out_size, void* d_ws, size_t ws_size,
                              hipStream_t stream)
{
  const float* src      = (const float*)d_in[0];
  const float* fnode    = (const float*)d_in[1];
  const float* fmess    = (const float*)d_in[2];
  const float* W_h      = (const float*)d_in[3];
  const float* U_h      = (const float*)d_in[4];
  const float* b_h      = (const float*)d_in[5];
  const float* W_o      = (const float*)d_in[6];
  const float* b_o      = (const float*)d_in[7];
  const float* topo_w1  = (const float*)d_in[8];
  const float* topo_b1  = (const float*)d_in[9];
  const float* topo_w2  = (const float*)d_in[10];
  const float* topo_b2  = (const float*)d_in[11];
  const float* atom_w1  = (const float*)d_in[12];
  const float* atom_b1  = (const float*)d_in[13];
  const float* atom_w2  = (const float*)d_in[14];
  const float* atom_b2  = (const float*)d_in[15];
  const float* bond_w1  = (const float*)d_in[16];
  const float* bond_b1  = (const float*)d_in[17];
  const float* bond_w2  = (const float*)d_in[18];
  const float* bond_b2  = (const float*)d_in[19];
  const float* rbond_w  = (const float*)d_in[20];
  const float* rbond_b  = (const float*)d_in[21];
  const float* wbond_w  = (const float*)d_in[22];
  const float* wbond_b  = (const float*)d_in[23];
  const int* agraph     = (const int*)d_in[24];
  const int* bgraph     = (const int*)d_in[25];
  const int* node2graph = (const int*)d_in[26];
  const int* emask      = (const int*)d_in[27];
  const int* vmask      = (const int*)d_in[28];
  const int* topo_step  = (const int*)d_in[29];
  const int* topo_bid   = (const int*)d_in[30];
  const int* topo_xid   = (const int*)d_in[31];
  const int* topo_label = (const int*)d_in[32];
  const int* atom_step  = (const int*)d_in[33];
  const int* atom_bid   = (const int*)d_in[34];
  const int* atom_xid   = (const int*)d_in[35];
  const int* atom_label = (const int*)d_in[36];
  const int* bond_step  = (const int*)d_in[37];
  const int* bond_bid   = (const int*)d_in[38];
  const int* bond_zid   = (const int*)d_in[39];
  const int* bond_atype = (const int*)d_in[40];
  const int* bond_label = (const int*)d_in[41];
  const int* bond_gs    = (const int*)d_in[42];

  char* wp = (char*)d_ws;
  auto alloc = [&](size_t bytes) -> char* {
    char* p = wp; wp += (bytes + 255) & ~(size_t)255; return p;
  };
  u16* preB  = (u16*)alloc((size_t)NE * 256 * 2);
  u16* hu1B  = (u16*)alloc((size_t)NE * 256 * 2);
  u16* foB   = (u16*)alloc((size_t)NN * 256 * 2);
  u16* bufA  = (u16*)alloc((size_t)NE * 256 * 2);
  u16* bufB  = (u16*)alloc((size_t)NE * 256 * 2);
  u16* nodeB = (u16*)alloc((size_t)NN * 256 * 2);
  int* bgm   = (int*)alloc((size_t)TT * NE * 6 * 4);
  int* agm   = (int*)alloc((size_t)TT * NN * 6 * 4);
  float* gvec = (float*)alloc((size_t)TT * BATCH * 256 * 4);
  u16* Wh_t  = (u16*)alloc(256 * 256 * 2);
  u16* Uh_t  = (u16*)alloc(256 * 256 * 2);
  u16* Wo1_t = (u16*)alloc(256 * 256 * 2);
  u16* Wo2_t = (u16*)alloc(256 * 256 * 2);
  u16* tw1_t = (u16*)alloc(256 * 544 * 2);
  u16* aw1_t = (u16*)alloc(256 * 544 * 2);
  u16* bw1_t = (u16*)alloc(256 * 800 * 2);
  u16* rw_t  = (u16*)alloc(256 * 320 * 2);
  u16* ww_t  = (u16*)alloc(256 * 288 * 2);
  u16* tv    = (u16*)alloc((size_t)PT * 544 * 2);
  u16* av    = (u16*)alloc((size_t)PA * 544 * 2);
  u16* bv    = (u16*)alloc((size_t)PB * 800 * 2);
  u16* wbin  = (u16*)alloc((size_t)PB * 288 * 2);
  u16* rbin  = (u16*)alloc((size_t)PB * 320 * 2);
  u16* wb    = (u16*)alloc((size_t)PB * 256 * 2);
  u16* t_hid = (u16*)alloc((size_t)PT * 256 * 2);
  u16* a_hid = (u16*)alloc((size_t)PA * 256 * 2);
  u16* b_hid = (u16*)alloc((size_t)PB * 256 * 2);

  float* out = (float*)d_out;
  hipMemsetAsync(out, 0, sizeof(float), stream);

#define GEMM(relu, Aptr, lda, M, Btptr, K, Cptr, ldc, biasptr)                              \
  do { dim3 g_(((M) + 127) / 128, 2);                                                       \
    if (relu) gemm_bt_kernel<1><<<g_, 256, 0, stream>>>((Aptr), (lda), (M), (Btptr), (K),   \
                                                        (Cptr), (ldc), (biasptr));          \
    else      gemm_bt_kernel<0><<<g_, 256, 0, stream>>>((Aptr), (lda), (M), (Btptr), (K),   \
                                                        (Cptr), (ldc), (biasptr));          \
  } while (0)

  // conversions (bufB <- bf16(fmess), nodeB <- bf16(fnode))
  cvt_f2b4_kernel<<<15000, 256, 0, stream>>>(fmess, bufB, (long)NE * 64);
  cvt_f2b4_kernel<<<7500, 256, 0, stream>>>(fnode, nodeB, (long)NN * 64);

  // weight transposes
  transpose_w_kernel<<<256, 256, 0, stream>>>(W_h, 256, 256, Wh_t);
  transpose_w_kernel<<<256, 256, 0, stream>>>(U_h, 256, 256, Uh_t);
  transpose_w_kernel<<<256, 256, 0, stream>>>(W_o, 256, 256, Wo1_t);
  transpose_w_kernel<<<256, 256, 0, stream>>>(W_o + 256 * 256, 256, 256, Wo2_t);
  transpose_w_kernel<<<544, 256, 0, stream>>>(topo_w1, 544, 544, tw1_t);
  transpose_w_kernel<<<544, 256, 0, stream>>>(atom_w1, 544, 544, aw1_t);
  transpose_w_kernel<<<800, 256, 0, stream>>>(bond_w1, 800, 800, bw1_t);
  transpose_w_kernel<<<320, 256, 0, stream>>>(rbond_w, 296, 320, rw_t);
  transpose_w_kernel<<<288, 256, 0, stream>>>(wbond_w, 260, 288, ww_t);

  // masked neighbor lists for all steps
  mask_kernel<<<dim3(1407, TT), 256, 0, stream>>>(bgraph, emask, bgm, NE * 6, NE);
  mask_kernel<<<dim3(704, TT), 256, 0, stream>>>(agraph, emask, agm, NN * 6, NE);

  // step-invariant precomputes
  GEMM(false, bufB, 256, NE, Wh_t, 256, preB, 256, nullptr);     // pre = fmess @ W_h
  h1_kernel<<<15000, 256, 0, stream>>>(preB, b_h, bufA);         // h1
  GEMM(false, bufA, 256, NE, Uh_t, 256, hu1B, 256, nullptr);     // hu1 = h1 @ U_h
  GEMM(false, nodeB, 256, NN, Wo1_t, 256, foB, 256, nullptr);    // fo = fnode @ W_o[:256]

  for (int t = 0; t < TT; t++) {
    const int* bgm_t = bgm + (size_t)t * NE * 6;
    const int* agm_t = agm + (size_t)t * NN * 6;
    // depth 2: H2 = relu(pre + gather(hu1) + b_h) * pad
    gather_e_kernel<<<15000, 256, 0, stream>>>(hu1B, preB, b_h, bgm_t, bufA);
    GEMM(false, bufA, 256, NE, Uh_t, 256, bufB, 256, nullptr);   // HU2
    // depth 3
    gather_e_kernel<<<15000, 256, 0, stream>>>(bufB, preB, b_h, bgm_t, bufA);
    GEMM(false, bufA, 256, NE, Uh_t, 256, bufB, 256, nullptr);   // HU3
    // depth 4
    gather_e_kernel<<<15000, 256, 0, stream>>>(bufB, preB, b_h, bgm_t, bufA);
    GEMM(false, bufA, 256, NE, Wo2_t, 256, bufB, 256, nullptr);  // HW = H4 @ W_o[256:]
    // node = relu(fo + gather(HW) + b_o) * vm
    gather_n_kernel<<<7500, 256, 0, stream>>>(bufB, foB, b_o, agm_t, vmask + (size_t)t * NN, nodeB);
    // graph vectors
    gvec_kernel<<<BATCH, 256, 0, stream>>>(nodeB, node2graph, gvec + (size_t)t * BATCH * 256);
    // scatter node rows of this step into head inputs
    head_gather_kernel<<<1344, 256, 0, stream>>>(t, nodeB,
        topo_step, topo_xid, atom_step, atom_xid, bond_step, bond_zid,
        tv, av, bv, wbin);
  }

  // static head-input segments
  build_static_kernel<<<1344, 256, 0, stream>>>(gvec, src,
      topo_step, topo_bid, atom_step, atom_bid, bond_step, bond_bid,
      bond_label, bond_atype, tv, av, bv, wbin, rbin);

  // heads
  GEMM(true, tv, 544, PT, tw1_t, 544, t_hid, 256, topo_b1);
  GEMM(true, av, 544, PA, aw1_t, 544, a_hid, 256, atom_b1);
  GEMM(true, wbin, 288, PB, ww_t, 288, wb, 256, wbond_b);
  hist_kernel<<<640, 256, 0, stream>>>(wb, bond_gs, bond_label, rbin);
  GEMM(true, rbin, 320, PB, rw_t, 320, bv + 256, 800, rbond_b);  // cur -> bv[:,256:512]
  GEMM(true, bv, 800, PB, bw1_t, 800, b_hid, 256, bond_b1);

  // losses
  topo_loss_kernel<<<384, 256, 0, stream>>>(t_hid, topo_w2, topo_b2, topo_label, out);
  ce_loss_kernel<VV><<<320, 256, 0, stream>>>(a_hid, atom_w2, atom_b2, atom_label, PA, out);
  ce_loss_kernel<NBOND><<<640, 256, 0, stream>>>(b_hid, bond_w2, bond_b2, bond_label, PB, out);

#undef GEMM
}

// Round 2
// 1489.750 us; speedup vs baseline: 1.2325x; 1.2325x over previous
//
#include <hip/hip_runtime.h>
#include <cstdint>
#include <cstddef>

using short8  = __attribute__((ext_vector_type(8))) short;
using floatx4 = __attribute__((ext_vector_type(4))) float;
typedef unsigned short u16;

constexpr int NN = 30000;   // nodes
constexpr int NE = 60000;   // edges / messages
constexpr int BATCH = 256;
constexpr int VV = 40;
constexpr int NBOND = 4;
constexpr int TT = 6;
constexpr int PT = 1536, PA = 1280, PB = 2560;

__device__ __forceinline__ float b2f(u16 h) {
  union { unsigned u; float f; } v; v.u = ((unsigned)h) << 16; return v.f;
}
__device__ __forceinline__ u16 f2b(float f) {
  union { float f; unsigned u; } v; v.f = f;
  unsigned r = v.u + 0x7FFFu + ((v.u >> 16) & 1u);
  return (u16)(r >> 16);
}
__device__ __forceinline__ float lo16(unsigned u) {
  union { unsigned x; float f; } v; v.x = u << 16; return v.f;
}
__device__ __forceinline__ float hi16(unsigned u) {
  union { unsigned x; float f; } v; v.x = u & 0xffff0000u; return v.f;
}
__device__ __forceinline__ unsigned pack2(float a, float b) {
  return ((unsigned)f2b(a)) | (((unsigned)f2b(b)) << 16);
}

// ---------------------------------------------------------------------------
// Generic bf16 MFMA GEMM:  C[M,256] = epilogue(A[M,K] @ B[K,256])
// A row-major bf16 (lda multiple of 8), Bt = B^T row-major bf16 [256,K].
// 128x128 tile per block, 4 waves in 2x2, 16x16x32 MFMA, BK=32.
// ---------------------------------------------------------------------------
template<int RELU_BIAS>
__global__ __launch_bounds__(256) void gemm_bt_kernel(
    const u16* __restrict__ A, int lda, int M,
    const u16* __restrict__ Bt, int K,
    u16* __restrict__ C, int ldc, const float* __restrict__ bias)
{
  __shared__ __align__(16) u16 As[128][56];
  __shared__ __align__(16) u16 Bs[128][56];
  const int tid  = threadIdx.x;
  const int wave = tid >> 6, lane = tid & 63;
  const int wm = wave >> 1, wn = wave & 1;
  const int lr = lane & 15, lk = (lane >> 4) * 8;
  const long rowbase = (long)blockIdx.x * 128;
  const int  colbase = blockIdx.y * 128;

  floatx4 acc[4][4];
#pragma unroll
  for (int i = 0; i < 4; i++)
#pragma unroll
    for (int j = 0; j < 4; j++) acc[i][j] = {0.f, 0.f, 0.f, 0.f};

  for (int k0 = 0; k0 < K; k0 += 32) {
#pragma unroll
    for (int r = 0; r < 2; r++) {
      int c = tid + 256 * r;
      int row = c >> 2, cc = (c & 3) * 8;
      long grow = rowbase + row;
      uint4 av = {0u, 0u, 0u, 0u};
      if (grow < M) av = *(const uint4*)(A + grow * (long)lda + k0 + cc);
      *(uint4*)(&As[row][cc]) = av;
      uint4 bv = *(const uint4*)(Bt + (long)(colbase + row) * K + k0 + cc);
      *(uint4*)(&Bs[row][cc]) = bv;
    }
    __syncthreads();
    short8 af[4], bf[4];
#pragma unroll
    for (int mt = 0; mt < 4; mt++) af[mt] = *(const short8*)(&As[wm * 64 + mt * 16 + lr][lk]);
#pragma unroll
    for (int nt = 0; nt < 4; nt++) bf[nt] = *(const short8*)(&Bs[wn * 64 + nt * 16 + lr][lk]);
#pragma unroll
    for (int mt = 0; mt < 4; mt++)
#pragma unroll
      for (int nt = 0; nt < 4; nt++)
        acc[mt][nt] = __builtin_amdgcn_mfma_f32_16x16x32_bf16(af[mt], bf[nt], acc[mt][nt], 0, 0, 0);
    __syncthreads();
  }

  const int rq = (lane >> 4) * 4;
#pragma unroll
  for (int mt = 0; mt < 4; mt++) {
#pragma unroll
    for (int nt = 0; nt < 4; nt++) {
      int gcol = colbase + wn * 64 + nt * 16 + lr;
#pragma unroll
      for (int r2 = 0; r2 < 4; r2++) {
        long grow = rowbase + wm * 64 + mt * 16 + rq + r2;
        if (grow < M) {
          float v = acc[mt][nt][r2];
          if (RELU_BIAS) { v += bias[gcol]; v = v > 0.f ? v : 0.f; }
          C[grow * (long)ldc + gcol] = f2b(v);
        }
      }
    }
  }
}

// ---------------------------------------------------------------------------
// small utility kernels
// ---------------------------------------------------------------------------
__global__ __launch_bounds__(256) void cvt_f2b4_kernel(const float* __restrict__ in,
                                                       u16* __restrict__ out, long n4)
{
  long i = (long)blockIdx.x * 256 + threadIdx.x;
  if (i >= n4) return;
  float4 v = ((const float4*)in)[i];
  ushort4 o; o.x = f2b(v.x); o.y = f2b(v.y); o.z = f2b(v.z); o.w = f2b(v.w);
  ((ushort4*)out)[i] = o;
}

// Bt[n][k] = bf16(W[k][n]), zero-padded k in [K, Kpad). W is [K,256] f32.
__global__ __launch_bounds__(256) void transpose_w_kernel(const float* __restrict__ W,
                                                          int K, int Kpad, u16* __restrict__ Bt)
{
  int idx = blockIdx.x * 256 + threadIdx.x;
  int total = 256 * Kpad;
  if (idx >= total) return;
  int n = idx / Kpad, k = idx - n * Kpad;
  Bt[idx] = (k < K) ? f2b(W[(long)k * 256 + n]) : (u16)0;
}

// masked neighbor lists: out[t][i] = graph[i] * em[t][graph[i]]
__global__ __launch_bounds__(256) void mask_kernel(const int* __restrict__ graph,
                                                   const int* __restrict__ em,
                                                   int* __restrict__ outm, int count, int estride)
{
  int t = blockIdx.y;
  int i = blockIdx.x * 256 + threadIdx.x;
  if (i >= count) return;
  int v = graph[i];
  outm[(long)t * count + i] = v * em[(long)t * estride + v];
}

// h1 = relu(pre + b_h) * pad
__global__ __launch_bounds__(256) void h1_kernel(const u16* __restrict__ pre,
                                                 const float* __restrict__ bh,
                                                 u16* __restrict__ out)
{
  long i = (long)blockIdx.x * 256 + threadIdx.x;
  if (i >= (long)NE * 64) return;
  int row = (int)(i >> 6);
  int c = ((int)i & 63) * 4;
  ushort4 p = *(const ushort4*)(pre + (long)row * 256 + c);
  float4 b = *(const float4*)(bh + c);
  float x0 = b2f(p.x) + b.x, x1 = b2f(p.y) + b.y, x2 = b2f(p.z) + b.z, x3 = b2f(p.w) + b.w;
  if (row == 0) { x0 = x1 = x2 = x3 = 0.f; }
  else { x0 = fmaxf(x0, 0.f); x1 = fmaxf(x1, 0.f); x2 = fmaxf(x2, 0.f); x3 = fmaxf(x3, 0.f); }
  ushort4 o; o.x = f2b(x0); o.y = f2b(x1); o.z = f2b(x2); o.w = f2b(x3);
  *(ushort4*)(out + (long)row * 256 + c) = o;
}

// ---------------------------------------------------------------------------
// batched gathers: 8 rows/block, 32 threads/row, 16B per thread
// ---------------------------------------------------------------------------
#define ACC8(gv) { a0 += lo16(gv.x); a1 += hi16(gv.x); a2 += lo16(gv.y); a3 += hi16(gv.y); \
                   a4 += lo16(gv.z); a5 += hi16(gv.z); a6 += lo16(gv.w); a7 += hi16(gv.w); }

// out[t][e] = relu(pre[e] + sum_j tab[t*tstride + idx[t][e][j]] + bias) * (e>0)
__global__ __launch_bounds__(256) void gather_e2_kernel(
    const u16* __restrict__ tab, long tstride, const u16* __restrict__ pre,
    const float* __restrict__ bias, const int* __restrict__ idx,
    u16* __restrict__ outp)
{
  constexpr int BPT = NE / 8;  // blocks per step
  int t = blockIdx.x / BPT;
  int e0 = (blockIdx.x - t * BPT) * 8;
  __shared__ int sidx[8][6];
  int tid = threadIdx.x;
  if (tid < 48) sidx[tid / 6][tid % 6] = idx[(long)t * NE * 6 + e0 * 6 + tid];
  __syncthreads();
  int rl = tid >> 5;
  int ch = (tid & 31) * 8;
  int e = e0 + rl;
  const u16* tb = tab + (long)t * tstride;
  uint4 p = *(const uint4*)(pre + (long)e * 256 + ch);
  float a0 = lo16(p.x), a1 = hi16(p.x), a2 = lo16(p.y), a3 = hi16(p.y);
  float a4 = lo16(p.z), a5 = hi16(p.z), a6 = lo16(p.w), a7 = hi16(p.w);
#pragma unroll
  for (int j = 0; j < 6; j++) {
    uint4 g = *(const uint4*)(tb + (long)sidx[rl][j] * 256 + ch);
    ACC8(g)
  }
  float4 b0 = *(const float4*)(bias + ch);
  float4 b1 = *(const float4*)(bias + ch + 4);
  a0 += b0.x; a1 += b0.y; a2 += b0.z; a3 += b0.w;
  a4 += b1.x; a5 += b1.y; a6 += b1.z; a7 += b1.w;
  if (e == 0) { a0 = a1 = a2 = a3 = a4 = a5 = a6 = a7 = 0.f; }
  else {
    a0 = fmaxf(a0, 0.f); a1 = fmaxf(a1, 0.f); a2 = fmaxf(a2, 0.f); a3 = fmaxf(a3, 0.f);
    a4 = fmaxf(a4, 0.f); a5 = fmaxf(a5, 0.f); a6 = fmaxf(a6, 0.f); a7 = fmaxf(a7, 0.f);
  }
  uint4 o; o.x = pack2(a0, a1); o.y = pack2(a2, a3); o.z = pack2(a4, a5); o.w = pack2(a6, a7);
  *(uint4*)(outp + ((long)t * NE + e) * 256 + ch) = o;
}

// node[t][n] = relu(fo[n] + sum_j tab[t*tstride + idx[t][n][j]] + b_o) * vm[t][n]
__global__ __launch_bounds__(256) void gather_n2_kernel(
    const u16* __restrict__ tab, long tstride, const u16* __restrict__ fo,
    const float* __restrict__ bias, const int* __restrict__ idx,
    const int* __restrict__ vm, u16* __restrict__ outp)
{
  constexpr int BPT = NN / 8;
  int t = blockIdx.x / BPT;
  int n0 = (blockIdx.x - t * BPT) * 8;
  __shared__ int sidx[8][6];
  __shared__ int svm[8];
  int tid = threadIdx.x;
  if (tid < 48) sidx[tid / 6][tid % 6] = idx[(long)t * NN * 6 + n0 * 6 + tid];
  if (tid >= 48 && tid < 56) svm[tid - 48] = vm[(long)t * NN + n0 + (tid - 48)];
  __syncthreads();
  int rl = tid >> 5;
  int ch = (tid & 31) * 8;
  int n = n0 + rl;
  const u16* tb = tab + (long)t * tstride;
  uint4 p = *(const uint4*)(fo + (long)n * 256 + ch);
  float a0 = lo16(p.x), a1 = hi16(p.x), a2 = lo16(p.y), a3 = hi16(p.y);
  float a4 = lo16(p.z), a5 = hi16(p.z), a6 = lo16(p.w), a7 = hi16(p.w);
#pragma unroll
  for (int j = 0; j < 6; j++) {
    uint4 g = *(const uint4*)(tb + (long)sidx[rl][j] * 256 + ch);
    ACC8(g)
  }
  float4 b0 = *(const float4*)(bias + ch);
  float4 b1 = *(const float4*)(bias + ch + 4);
  a0 += b0.x; a1 += b0.y; a2 += b0.z; a3 += b0.w;
  a4 += b1.x; a5 += b1.y; a6 += b1.z; a7 += b1.w;
  a0 = fmaxf(a0, 0.f); a1 = fmaxf(a1, 0.f); a2 = fmaxf(a2, 0.f); a3 = fmaxf(a3, 0.f);
  a4 = fmaxf(a4, 0.f); a5 = fmaxf(a5, 0.f); a6 = fmaxf(a6, 0.f); a7 = fmaxf(a7, 0.f);
  if (svm[rl] == 0) { a0 = a1 = a2 = a3 = a4 = a5 = a6 = a7 = 0.f; }
  uint4 o; o.x = pack2(a0, a1); o.y = pack2(a2, a3); o.z = pack2(a4, a5); o.w = pack2(a6, a7);
  *(uint4*)(outp + ((long)t * NN + n) * 256 + ch) = o;
}
#undef ACC8

__device__ __forceinline__ int lbound(const int* __restrict__ a, int n, int key) {
  int lo = 0, hi = n;
  while (lo < hi) { int mid = (lo + hi) >> 1; if (a[mid] < key) lo = mid + 1; else hi = mid; }
  return lo;
}

// gv[t0+tl][b][h] = segment-sum of node chunk tl
__global__ __launch_bounds__(256) void gvec_kernel(const u16* __restrict__ node,
                                                   const int* __restrict__ n2g,
                                                   float* __restrict__ gv, int t0)
{
  int b = blockIdx.x, h = threadIdx.x, tl = blockIdx.y;
  int lo = lbound(n2g, NN, b), hi = lbound(n2g, NN, b + 1);
  const u16* nd = node + (long)tl * NN * 256;
  float s = 0.f;
  for (int n = lo; n < hi; n++) s += b2f(nd[(long)n * 256 + h]);
  gv[((long)(t0 + tl) * BATCH + b) * 256 + h] = s;
}

// scatter node rows with step in [t0, t0+TB) into head-input matrices
__global__ __launch_bounds__(256) void head_gather_kernel(int t0, int TB,
    const u16* __restrict__ node,
    const int* __restrict__ tstep, const int* __restrict__ txid,
    const int* __restrict__ astep, const int* __restrict__ axid,
    const int* __restrict__ bstep, const int* __restrict__ bzid,
    u16* __restrict__ tv, u16* __restrict__ av, u16* __restrict__ bv,
    u16* __restrict__ wbin)
{
  int wave = threadIdx.x >> 6, lane = threadIdx.x & 63;
  int r = blockIdx.x * 4 + wave;
  int c = lane * 4;
  if (r < PT) {
    int st = tstep[r];
    if (st < t0 || st >= t0 + TB) return;
    ushort4 v = *(const ushort4*)(node + ((long)(st - t0) * NN + txid[r]) * 256 + c);
    *(ushort4*)(tv + (long)r * 544 + 256 + c) = v;
  } else if (r < PT + PA) {
    int i = r - PT;
    int st = astep[i];
    if (st < t0 || st >= t0 + TB) return;
    ushort4 v = *(const ushort4*)(node + ((long)(st - t0) * NN + axid[i]) * 256 + c);
    *(ushort4*)(av + (long)i * 544 + 256 + c) = v;
  } else if (r < PT + PA + PB) {
    int i = r - PT - PA;
    int st = bstep[i];
    if (st < t0 || st >= t0 + TB) return;
    ushort4 v = *(const ushort4*)(node + ((long)(st - t0) * NN + bzid[i]) * 256 + c);
    *(ushort4*)(bv + (long)i * 800 + 512 + c) = v;
    *(ushort4*)(wbin + (long)i * 288 + c) = v;
  }
}

// fill gvec / src / one-hot segments of head inputs (after all steps)
__global__ __launch_bounds__(256) void build_static_kernel(
    const float* __restrict__ gvec, const float* __restrict__ src,
    const int* __restrict__ tstep, const int* __restrict__ tbid,
    const int* __restrict__ astep, const int* __restrict__ abid,
    const int* __restrict__ bstep, const int* __restrict__ bbid,
    const int* __restrict__ blabel, const int* __restrict__ batype,
    u16* __restrict__ tv, u16* __restrict__ av, u16* __restrict__ bv,
    u16* __restrict__ wbin, u16* __restrict__ rbin)
{
  int wave = threadIdx.x >> 6, lane = threadIdx.x & 63;
  int r = blockIdx.x * 4 + wave;
  int c = lane * 4;
  if (r < PT) {
    int st = tstep[r], bid = tbid[r];
    const float* g = gvec + ((long)st * BATCH + bid) * 256;
    u16* d = tv + (long)r * 544;
    float4 g4 = *(const float4*)(g + c);
    d[c] = f2b(g4.x); d[c + 1] = f2b(g4.y); d[c + 2] = f2b(g4.z); d[c + 3] = f2b(g4.w);
    if (lane < 8) {
      float4 s4 = *(const float4*)(src + bid * 32 + c);
      d[512 + c] = f2b(s4.x); d[512 + c + 1] = f2b(s4.y);
      d[512 + c + 2] = f2b(s4.z); d[512 + c + 3] = f2b(s4.w);
    }
  } else if (r < PT + PA) {
    int i = r - PT;
    int st = astep[i], bid = abid[i];
    const float* g = gvec + ((long)st * BATCH + bid) * 256;
    u16* d = av + (long)i * 544;
    float4 g4 = *(const float4*)(g + c);
    d[c] = f2b(g4.x); d[c + 1] = f2b(g4.y); d[c + 2] = f2b(g4.z); d[c + 3] = f2b(g4.w);
    if (lane < 8) {
      float4 s4 = *(const float4*)(src + bid * 32 + c);
      d[512 + c] = f2b(s4.x); d[512 + c + 1] = f2b(s4.y);
      d[512 + c + 2] = f2b(s4.z); d[512 + c + 3] = f2b(s4.w);
    }
  } else if (r < PT + PA + PB) {
    int i = r - PT - PA;
    int st = bstep[i], bid = bbid[i];
    const float* g = gvec + ((long)st * BATCH + bid) * 256;
    u16* d = bv + (long)i * 800;
    float4 g4 = *(const float4*)(g + c);
    d[c] = f2b(g4.x); d[c + 1] = f2b(g4.y); d[c + 2] = f2b(g4.z); d[c + 3] = f2b(g4.w);
    if (lane < 8) {
      float4 s4 = *(const float4*)(src + bid * 32 + c);
      d[768 + c] = f2b(s4.x); d[768 + c + 1] = f2b(s4.y);
      d[768 + c + 2] = f2b(s4.z); d[768 + c + 3] = f2b(s4.w);
      int bl = blabel[i];
      u16* wd = wbin + (long)i * 288 + 256;
      for (int q = 0; q < 4; q++) {
        int k = c + q;
        wd[k] = f2b((k < NBOND && bl == k) ? 1.f : 0.f);
      }
    }
    if (lane < 16) {
      int at = batype[i];
      u16* rd = rbin + (long)i * 320 + 256;
      for (int q = 0; q < 4; q++) {
        int k = c + q;
        rd[k] = f2b((k < VV && at == k) ? 1.f : 0.f);
      }
    }
  }
}

// rbin[r][0:256] = sum_{j in [gs[r], r)} wb[j] * (blabel[j] > 0)
__global__ __launch_bounds__(256) void hist_kernel(
    const u16* __restrict__ wb, const int* __restrict__ gs_arr,
    const int* __restrict__ blabel, u16* __restrict__ rbin)
{
  int wave = threadIdx.x >> 6, lane = threadIdx.x & 63;
  int r = blockIdx.x * 4 + wave;
  if (r >= PB) return;
  int c = lane * 4;
  float a0 = 0.f, a1 = 0.f, a2 = 0.f, a3 = 0.f;
  int gs = gs_arr[r];
  for (int j = gs; j < r; j++) {
    if (blabel[j] > 0) {
      ushort4 g = *(const ushort4*)(wb + (long)j * 256 + c);
      a0 += b2f(g.x); a1 += b2f(g.y); a2 += b2f(g.z); a3 += b2f(g.w);
    }
  }
  u16* rd = rbin + (long)r * 320;
  rd[c] = f2b(a0); rd[c + 1] = f2b(a1); rd[c + 2] = f2b(a2); rd[c + 3] = f2b(a3);
}

// topo: BCE-with-logits, one wave per row
__global__ __launch_bounds__(256) void topo_loss_kernel(
    const u16* __restrict__ hidden, const float* __restrict__ w2,
    const float* __restrict__ b2, const int* __restrict__ label,
    float* __restrict__ out)
{
  int wave = threadIdx.x >> 6, lane = threadIdx.x & 63;
  int r = blockIdx.x * 4 + wave;
  if (r >= PT) return;
  const u16* h = hidden + (long)r * 256;
  int c = lane * 4;
  ushort4 hv = *(const ushort4*)(h + c);
  float4 wv = *(const float4*)(w2 + c);
  float s = b2f(hv.x) * wv.x + b2f(hv.y) * wv.y + b2f(hv.z) * wv.z + b2f(hv.w) * wv.w;
#pragma unroll
  for (int off = 32; off > 0; off >>= 1) s += __shfl_xor(s, off);
  if (lane == 0) {
    float l = s + b2[0];
    float y = (float)label[r];
    float sp = fmaxf(l, 0.f) + log1pf(expf(-fabsf(l)));
    atomicAdd(out, (sp - l * y) * (1.0f / BATCH));
  }
}

// cross-entropy over NC classes (NC<=64): w2 cached in LDS, h row vectorized,
// shuffle-broadcast so every lane's loads are wide and independent.
template<int NC>
__global__ __launch_bounds__(256) void ce_loss_kernel(
    const u16* __restrict__ hidden, const float* __restrict__ w2,
    const float* __restrict__ b2, const int* __restrict__ label,
    int rows, float* __restrict__ out)
{
  __shared__ float w2s[256 * NC];
  for (int i = threadIdx.x; i < 256 * NC; i += 256) w2s[i] = w2[i];
  __syncthreads();
  int wave = threadIdx.x >> 6, lane = threadIdx.x & 63;
  int r = blockIdx.x * 4 + wave;
  if (r >= rows) return;
  const u16* h = hidden + (long)r * 256;
  ushort4 hv4 = *(const ushort4*)(h + lane * 4);
  float h0 = b2f(hv4.x), h1 = b2f(hv4.y), h2 = b2f(hv4.z), h3 = b2f(hv4.w);
  bool valid = lane < NC;
  float s = valid ? b2[lane] : 0.f;
#pragma unroll 8
  for (int j = 0; j < 64; j++) {
    float a0 = __shfl(h0, j), a1 = __shfl(h1, j), a2 = __shfl(h2, j), a3 = __shfl(h3, j);
    if (valid) {
      int c = j * 4;
      s += a0 * w2s[c * NC + lane] + a1 * w2s[(c + 1) * NC + lane]
         + a2 * w2s[(c + 2) * NC + lane] + a3 * w2s[(c + 3) * NC + lane];
    }
  }
  float logit = valid ? s : -1e30f;
  float m = logit;
#pragma unroll
  for (int off = 32; off > 0; off >>= 1) m = fmaxf(m, __shfl_xor(m, off));
  float e = valid ? expf(logit - m) : 0.f;
#pragma unroll
  for (int off = 32; off > 0; off >>= 1) e += __shfl_xor(e, off);
  float lse = m + logf(e);
  int lb = label[r];
  float ll = __shfl(logit, lb);
  if (lane == 0) atomicAdd(out, (lse - ll) * (1.0f / BATCH));
}

// ---------------------------------------------------------------------------
extern "C" void kernel_launch(void* const* d_in, const int* in_sizes, int n_in,
                              void* d_out, int out_size, void* d_ws, size_t ws_size,
                              hipStream_t stream)
{
  const float* src      = (const float*)d_in[0];
  const float* fnode    = (const float*)d_in[1];
  const float* fmess    = (const float*)d_in[2];
  const float* W_h      = (const float*)d_in[3];
  const float* U_h      = (const float*)d_in[4];
  const float* b_h      = (const float*)d_in[5];
  const float* W_o      = (const float*)d_in[6];
  const float* b_o      = (const float*)d_in[7];
  const float* topo_w1  = (const float*)d_in[8];
  const float* topo_b1  = (const float*)d_in[9];
  const float* topo_w2  = (const float*)d_in[10];
  const float* topo_b2  = (const float*)d_in[11];
  const float* atom_w1  = (const float*)d_in[12];
  const float* atom_b1  = (const float*)d_in[13];
  const float* atom_w2  = (const float*)d_in[14];
  const float* atom_b2  = (const float*)d_in[15];
  const float* bond_w1  = (const float*)d_in[16];
  const float* bond_b1  = (const float*)d_in[17];
  const float* bond_w2  = (const float*)d_in[18];
  const float* bond_b2  = (const float*)d_in[19];
  const float* rbond_w  = (const float*)d_in[20];
  const float* rbond_b  = (const float*)d_in[21];
  const float* wbond_w  = (const float*)d_in[22];
  const float* wbond_b  = (const float*)d_in[23];
  const int* agraph     = (const int*)d_in[24];
  const int* bgraph     = (const int*)d_in[25];
  const int* node2graph = (const int*)d_in[26];
  const int* emask      = (const int*)d_in[27];
  const int* vmask      = (const int*)d_in[28];
  const int* topo_step  = (const int*)d_in[29];
  const int* topo_bid   = (const int*)d_in[30];
  const int* topo_xid   = (const int*)d_in[31];
  const int* topo_label = (const int*)d_in[32];
  const int* atom_step  = (const int*)d_in[33];
  const int* atom_bid   = (const int*)d_in[34];
  const int* atom_xid   = (const int*)d_in[35];
  const int* atom_label = (const int*)d_in[36];
  const int* bond_step  = (const int*)d_in[37];
  const int* bond_bid   = (const int*)d_in[38];
  const int* bond_zid   = (const int*)d_in[39];
  const int* bond_atype = (const int*)d_in[40];
  const int* bond_label = (const int*)d_in[41];
  const int* bond_gs    = (const int*)d_in[42];

  char* wp = (char*)d_ws;
  auto alloc = [&](size_t bytes) -> char* {
    char* p = wp; wp += (bytes + 255) & ~(size_t)255; return p;
  };
  // fixed allocations
  u16* preB   = (u16*)alloc((size_t)NE * 256 * 2);
  u16* hu1B   = (u16*)alloc((size_t)NE * 256 * 2);
  u16* foB    = (u16*)alloc((size_t)NN * 256 * 2);
  int* bgm    = (int*)alloc((size_t)TT * NE * 6 * 4);
  int* agm    = (int*)alloc((size_t)TT * NN * 6 * 4);
  float* gvec = (float*)alloc((size_t)TT * BATCH * 256 * 4);
  u16* Wh_t   = (u16*)alloc(256 * 256 * 2);
  u16* Uh_t   = (u16*)alloc(256 * 256 * 2);
  u16* Wo1_t  = (u16*)alloc(256 * 256 * 2);
  u16* Wo2_t  = (u16*)alloc(256 * 256 * 2);
  u16* tw1_t  = (u16*)alloc(256 * 544 * 2);
  u16* aw1_t  = (u16*)alloc(256 * 544 * 2);
  u16* bw1_t  = (u16*)alloc(256 * 800 * 2);
  u16* rw_t   = (u16*)alloc(256 * 320 * 2);
  u16* ww_t   = (u16*)alloc(256 * 288 * 2);
  u16* tv     = (u16*)alloc((size_t)PT * 544 * 2);
  u16* av     = (u16*)alloc((size_t)PA * 544 * 2);
  u16* bv     = (u16*)alloc((size_t)PB * 800 * 2);
  u16* wbin   = (u16*)alloc((size_t)PB * 288 * 2);
  u16* rbin   = (u16*)alloc((size_t)PB * 320 * 2);
  u16* wb     = (u16*)alloc((size_t)PB * 256 * 2);
  u16* t_hid  = (u16*)alloc((size_t)PT * 256 * 2);
  u16* a_hid  = (u16*)alloc((size_t)PA * 256 * 2);
  u16* b_hid  = (u16*)alloc((size_t)PB * 256 * 2);

  // chunked (per-TB-steps) buffers: pick largest TB in {6,3,2,1} that fits
  size_t used = (size_t)(wp - (char*)d_ws);
  size_t per_tb = ((size_t)NE * 256 * 2) * 2 + (size_t)NN * 256 * 2 + 3 * 256;
  size_t remain = (ws_size > used) ? (ws_size - used) : 0;
  int TB = 1;
  if (6 * per_tb <= remain) TB = 6;
  else if (3 * per_tb <= remain) TB = 3;
  else if (2 * per_tb <= remain) TB = 2;
  u16* bufA  = (u16*)alloc((size_t)TB * NE * 256 * 2);
  u16* bufB  = (u16*)alloc((size_t)TB * NE * 256 * 2);
  u16* nodeB = (u16*)alloc((size_t)TB * NN * 256 * 2);

  float* out = (float*)d_out;
  hipMemsetAsync(out, 0, sizeof(float), stream);

#define GEMM(relu, Aptr, lda, M, Btptr, K, Cptr, ldc, biasptr)                              \
  do { dim3 g_(((M) + 127) / 128, 2);                                                       \
    if (relu) gemm_bt_kernel<1><<<g_, 256, 0, stream>>>((Aptr), (lda), (M), (Btptr), (K),   \
                                                        (Cptr), (ldc), (biasptr));          \
    else      gemm_bt_kernel<0><<<g_, 256, 0, stream>>>((Aptr), (lda), (M), (Btptr), (K),   \
                                                        (Cptr), (ldc), (biasptr));          \
  } while (0)

  // conversions (bufA <- bf16(fmess), foB staging via nodeB-area is not safe; use bufB)
  cvt_f2b4_kernel<<<15000, 256, 0, stream>>>(fmess, bufA, (long)NE * 64);
  cvt_f2b4_kernel<<<7500, 256, 0, stream>>>(fnode, bufB, (long)NN * 64);

  // weight transposes
  transpose_w_kernel<<<256, 256, 0, stream>>>(W_h, 256, 256, Wh_t);
  transpose_w_kernel<<<256, 256, 0, stream>>>(U_h, 256, 256, Uh_t);
  transpose_w_kernel<<<256, 256, 0, stream>>>(W_o, 256, 256, Wo1_t);
  transpose_w_kernel<<<256, 256, 0, stream>>>(W_o + 256 * 256, 256, 256, Wo2_t);
  transpose_w_kernel<<<544, 256, 0, stream>>>(topo_w1, 544, 544, tw1_t);
  transpose_w_kernel<<<544, 256, 0, stream>>>(atom_w1, 544, 544, aw1_t);
  transpose_w_kernel<<<800, 256, 0, stream>>>(bond_w1, 800, 800, bw1_t);
  transpose_w_kernel<<<320, 256, 0, stream>>>(rbond_w, 296, 320, rw_t);
  transpose_w_kernel<<<288, 256, 0, stream>>>(wbond_w, 260, 288, ww_t);

  // masked neighbor lists for all steps
  mask_kernel<<<dim3(1407, TT), 256, 0, stream>>>(bgraph, emask, bgm, NE * 6, NE);
  mask_kernel<<<dim3(704, TT), 256, 0, stream>>>(agraph, emask, agm, NN * 6, NE);

  // step-invariant precomputes
  GEMM(false, bufA, 256, NE, Wh_t, 256, preB, 256, nullptr);     // pre = fmess @ W_h
  GEMM(false, bufB, 256, NN, Wo1_t, 256, foB, 256, nullptr);     // fo = fnode @ W_o[:256]
  h1_kernel<<<15000, 256, 0, stream>>>(preB, b_h, bufA);         // h1
  GEMM(false, bufA, 256, NE, Uh_t, 256, hu1B, 256, nullptr);     // hu1 = h1 @ U_h

  for (int t0 = 0; t0 < TT; t0 += TB) {
    const int* bgm_c = bgm + (size_t)t0 * NE * 6;
    const int* agm_c = agm + (size_t)t0 * NN * 6;
    int geb = TB * (NE / 8);   // gather_e blocks
    int gnb = TB * (NN / 8);   // gather_n blocks
    int M = TB * NE;
    // depth 2: H2 = relu(pre + gather(hu1) + b_h) * pad   (hu1 shared across t)
    gather_e2_kernel<<<geb, 256, 0, stream>>>(hu1B, 0, preB, b_h, bgm_c, bufA);
    GEMM(false, bufA, 256, M, Uh_t, 256, bufB, 256, nullptr);
    // depth 3
    gather_e2_kernel<<<geb, 256, 0, stream>>>(bufB, (long)NE * 256, preB, b_h, bgm_c, bufA);
    GEMM(false, bufA, 256, M, Uh_t, 256, bufB, 256, nullptr);
    // depth 4 (+ fold W_o[256:] into the GEMM)
    gather_e2_kernel<<<geb, 256, 0, stream>>>(bufB, (long)NE * 256, preB, b_h, bgm_c, bufA);
    GEMM(false, bufA, 256, M, Wo2_t, 256, bufB, 256, nullptr);
    // node = relu(fo + gather(HW) + b_o) * vm
    gather_n2_kernel<<<gnb, 256, 0, stream>>>(bufB, (long)NE * 256, foB, b_o, agm_c,
                                              vmask + (size_t)t0 * NN, nodeB);
    // graph vectors for this chunk
    gvec_kernel<<<dim3(BATCH, TB), 256, 0, stream>>>(nodeB, node2graph, gvec, t0);
    // scatter node rows into head inputs
    head_gather_kernel<<<1344, 256, 0, stream>>>(t0, TB, nodeB,
        topo_step, topo_xid, atom_step, atom_xid, bond_step, bond_zid,
        tv, av, bv, wbin);
  }

  // static head-input segments
  build_static_kernel<<<1344, 256, 0, stream>>>(gvec, src,
      topo_step, topo_bid, atom_step, atom_bid, bond_step, bond_bid,
      bond_label, bond_atype, tv, av, bv, wbin, rbin);

  // heads
  GEMM(true, tv, 544, PT, tw1_t, 544, t_hid, 256, topo_b1);
  GEMM(true, av, 544, PA, aw1_t, 544, a_hid, 256, atom_b1);
  GEMM(true, wbin, 288, PB, ww_t, 288, wb, 256, wbond_b);
  hist_kernel<<<640, 256, 0, stream>>>(wb, bond_gs, bond_label, rbin);
  GEMM(true, rbin, 320, PB, rw_t, 320, bv + 256, 800, rbond_b);  // cur -> bv[:,256:512]
  GEMM(true, bv, 800, PB, bw1_t, 800, b_hid, 256, bond_b1);

  // losses
  topo_loss_kernel<<<384, 256, 0, stream>>>(t_hid, topo_w2, topo_b2, topo_label, out);
  ce_loss_kernel<VV><<<320, 256, 0, stream>>>(a_hid, atom_w2, atom_b2, atom_label, PA, out);
  ce_loss_kernel<NBOND><<<640, 256, 0, stream>>>(b_hid, bond_w2, bond_b2, bond_label, PB, out);

#undef GEMM
}